// Round 4
// baseline (569.680 us; speedup 1.0000x reference)
//
#include <hip/hip_runtime.h>
#include <hip/hip_bf16.h>

#define DD 128    // feature dim
#define HH 16     // hidden dim
#define BW 128    // bucket width (nodes per bucket), = 1<<7
#define NBMAX 1024

// ---------------------------------------------------------------------------
// K0: collapse layer-2 + classifier into 16-dim vectors.
//   wsu[0..15]  = w2_l[j,:].wc[:128]    wsu[16..31] = w2_l[j,:].wc[128:]
//   wsu[32..47] = w2_r[j,:].wc[:128]    wsu[48..63] = w2_r[j,:].wc[128:]
//   wsu[64] = b2.wc[:128] + bc ;  wsu[65] = b2.wc[128:]
// ---------------------------------------------------------------------------
__global__ void k_prep(const float* __restrict__ w2l, const float* __restrict__ w2r,
                       const float* __restrict__ b2v, const float* __restrict__ wc,
                       const float* __restrict__ bc, float* __restrict__ wsu) {
    int t = threadIdx.x;
    if (t < 64) {
        int k = t >> 4, j = t & 15;
        const float* W = (k < 2) ? w2l : w2r;
        int off = (k & 1) * DD;
        float s = 0.f;
        for (int d = 0; d < DD; ++d) s += W[j * DD + d] * wc[off + d];
        wsu[k * 16 + j] = s;
    } else if (t == 64) {
        float s = bc[0];
        for (int d = 0; d < DD; ++d) s += b2v[d] * wc[d];
        wsu[64] = s;
    } else if (t == 65) {
        float s = 0.f;
        for (int d = 0; d < DD; ++d) s += b2v[d] * wc[DD + d];
        wsu[65] = s;
    }
}

// ---------------------------------------------------------------------------
// K1: y1 = x @ w1_l, z1 = x @ w1_r   (x: [N,128] f32 -> y1,z1: [N,16] f32)
// ---------------------------------------------------------------------------
__global__ __launch_bounds__(256) void k_xform(const float* __restrict__ x,
                                               const float* __restrict__ w1l,
                                               const float* __restrict__ w1r,
                                               float* __restrict__ y1,
                                               float* __restrict__ z1, int N) {
    __shared__ float wl[DD * HH];
    __shared__ float wr[DD * HH];
    __shared__ float xt[16 * 132];    // row stride 132 floats (33 float4)

    const int tid  = threadIdx.x;
    const int row0 = blockIdx.x * 16;

    {
        const float4* a = (const float4*)w1l;
        const float4* b = (const float4*)w1r;
        ((float4*)wl)[tid]       = a[tid];
        ((float4*)wl)[tid + 256] = a[tid + 256];
        ((float4*)wr)[tid]       = b[tid];
        ((float4*)wr)[tid + 256] = b[tid + 256];
    }
    {
        for (int k = 0; k < 2; ++k) {
            int idx = tid + k * 256;
            int r = idx >> 5, seg = idx & 31;
            if (row0 + r < N) {
                float4 v = ((const float4*)(x + (size_t)(row0 + r) * DD))[seg];
                ((float4*)xt)[r * 33 + seg] = v;
            }
        }
    }
    __syncthreads();

    const int r = tid >> 4, j = tid & 15;
    const int row = row0 + r;
    if (row >= N) return;
    float accy = 0.f, accz = 0.f;
#pragma unroll 8
    for (int d = 0; d < DD; ++d) {
        float xv = xt[r * 132 + d];
        accy += xv * wl[d * HH + j];
        accz += xv * wr[d * HH + j];
    }
    y1[(size_t)row * HH + j] = accy;
    z1[(size_t)row * HH + j] = accz;
}

// ---------------------------------------------------------------------------
// K2: per-bucket histogram. 8192 edges/block, LDS hist, one global
// atomicAdd per (block,bucket).
// ---------------------------------------------------------------------------
__global__ __launch_bounds__(256) void k_bcount(const int* __restrict__ dst,
                                                int* __restrict__ bcnt,
                                                int E4, int NB) {
    __shared__ int hist[NBMAX];
    for (int i = threadIdx.x; i < NB; i += 256) hist[i] = 0;
    __syncthreads();
    int base = blockIdx.x * 2048;
#pragma unroll
    for (int k = 0; k < 8; ++k) {
        int i4 = base + k * 256 + threadIdx.x;
        if (i4 < E4) {
            int4 d = ((const int4*)dst)[i4];
            atomicAdd(&hist[d.x >> 7], 1);
            atomicAdd(&hist[d.y >> 7], 1);
            atomicAdd(&hist[d.z >> 7], 1);
            atomicAdd(&hist[d.w >> 7], 1);
        }
    }
    __syncthreads();
    for (int i = threadIdx.x; i < NB; i += 256) {
        int h = hist[i];
        if (h) atomicAdd(&bcnt[i], h);
    }
}

// ---------------------------------------------------------------------------
// K3: exclusive scan over NB bucket counts -> bstart, gcursor (single block)
// ---------------------------------------------------------------------------
__global__ __launch_bounds__(1024) void k_bscan(const int* __restrict__ bcnt,
                                                int* __restrict__ bstart,
                                                int* __restrict__ gcursor, int NB) {
    __shared__ int sa[1024];
    __shared__ int sb[1024];
    int t = threadIdx.x;
    int v = (t < NB) ? bcnt[t] : 0;
    sa[t] = v;
    __syncthreads();
    int* cur = sa;
    int* nxt = sb;
    for (int off = 1; off < 1024; off <<= 1) {
        int xv = cur[t];
        if (t >= off) xv += cur[t - off];
        nxt[t] = xv;
        __syncthreads();
        int* tmp = cur; cur = nxt; nxt = tmp;
    }
    if (t < NB) {
        int excl = cur[t] - v;
        bstart[t] = excl;
        gcursor[t] = excl;
    }
}

// ---------------------------------------------------------------------------
// K4: bucketed scatter. Per chunk: LDS hist -> bulk range reservation ->
// packed entries (local<<20 | src). Writes land in ~contiguous per-bucket
// ranges -> no 16x line amplification.
// ---------------------------------------------------------------------------
__global__ __launch_bounds__(256) void k_bscatter(const int* __restrict__ src,
                                                  const int* __restrict__ dst,
                                                  int* __restrict__ gcursor,
                                                  int* __restrict__ csr,
                                                  int E4, int NB) {
    __shared__ int hist[NBMAX];
    __shared__ int cur[NBMAX];
    for (int i = threadIdx.x; i < NB; i += 256) hist[i] = 0;
    __syncthreads();
    int base = blockIdx.x * 2048;
    int4 dreg[8];
#pragma unroll
    for (int k = 0; k < 8; ++k) {
        int i4 = base + k * 256 + threadIdx.x;
        if (i4 < E4) {
            int4 d = ((const int4*)dst)[i4];
            dreg[k] = d;
            atomicAdd(&hist[d.x >> 7], 1);
            atomicAdd(&hist[d.y >> 7], 1);
            atomicAdd(&hist[d.z >> 7], 1);
            atomicAdd(&hist[d.w >> 7], 1);
        }
    }
    __syncthreads();
    for (int i = threadIdx.x; i < NB; i += 256) {
        int h = hist[i];
        cur[i] = h ? atomicAdd(&gcursor[i], h) : 0;
    }
    __syncthreads();
#pragma unroll
    for (int k = 0; k < 8; ++k) {
        int i4 = base + k * 256 + threadIdx.x;
        if (i4 < E4) {
            int4 s = ((const int4*)src)[i4];
            int4 d = dreg[k];
            int p;
            p = atomicAdd(&cur[d.x >> 7], 1); csr[p] = ((d.x & 127) << 20) | s.x;
            p = atomicAdd(&cur[d.y >> 7], 1); csr[p] = ((d.y & 127) << 20) | s.y;
            p = atomicAdd(&cur[d.z >> 7], 1); csr[p] = ((d.z & 127) << 20) | s.z;
            p = atomicAdd(&cur[d.w >> 7], 1); csr[p] = ((d.w & 127) << 20) | s.w;
        }
    }
}

// ---------------------------------------------------------------------------
// K5: bucketed segment mean via LDS accumulation. One block per bucket.
// mode 0: out = relu(sum/deg + b1 + z1), also writes invdeg (deg from LDS)
// mode 1: out = sum * invdeg
// ---------------------------------------------------------------------------
__global__ __launch_bounds__(256) void k_bagg(const int* __restrict__ csr,
                                              const int* __restrict__ bstart,
                                              const int* __restrict__ bcnt,
                                              const float* __restrict__ feat,
                                              const float* __restrict__ z1,
                                              const float* __restrict__ b1,
                                              float* __restrict__ invdeg,
                                              float* __restrict__ outv,
                                              int N, int mode) {
    __shared__ float acc[BW * HH];     // 8 KB
    __shared__ float degc[BW];
    int tid = threadIdx.x;
    for (int i = tid; i < BW * HH; i += 256) acc[i] = 0.f;
    if (tid < BW) degc[tid] = 0.f;
    __syncthreads();

    int b = blockIdx.x;
    int st = bstart[b], cnt = bcnt[b];
    int g = tid >> 4, j = tid & 15;
#pragma unroll 4
    for (int k = g; k < cnt; k += 16) {
        int e = csr[st + k];
        int s = e & 0xFFFFF, local = e >> 20;
        float v = feat[(size_t)s * HH + j];
        atomicAdd(&acc[(local << 4) + j], v);
        if (j == 0) atomicAdd(&degc[local], 1.f);
    }
    __syncthreads();

    int node0 = b << 7;
    if (mode == 0) {
        for (int i = tid; i < BW * HH; i += 256) {
            int local = i >> 4, jj = i & 15;
            int node = node0 + local;
            if (node < N) {
                float inv = 1.f / fmaxf(degc[local], 1.f);
                size_t o = (size_t)node * HH + jj;
                float v = acc[i] * inv + b1[jj] + z1[o];
                outv[o] = fmaxf(v, 0.f);
                if (jj == 0) invdeg[node] = inv;
            }
        }
    } else {
        for (int i = tid; i < BW * HH; i += 256) {
            int local = i >> 4;
            int node = node0 + local;
            if (node < N)
                outv[(size_t)node * HH + (i & 15)] = acc[i] * invdeg[node];
        }
    }
}

// ---------------------------------------------------------------------------
// K6: per-pair logits + BCE partial sums. 16 lanes per pair.
// ---------------------------------------------------------------------------
__global__ __launch_bounds__(256) void k_pair(const float* __restrict__ h,
                                              const float* __restrict__ aggs,
                                              const int* __restrict__ a1,
                                              const int* __restrict__ a2,
                                              const int* __restrict__ labels,
                                              const float* __restrict__ wsu,
                                              float* __restrict__ out_logits,
                                              float* __restrict__ lacc, int B) {
    __shared__ float lred[16];
    int t = blockIdx.x * 256 + threadIdx.x;
    int p = t >> 4, j = t & 15;
    int g = threadIdx.x >> 4;

    float myloss = 0.f;
    if (p < B) {
        int i1 = a1[p], i2 = a2[p];
        float v = aggs[(size_t)i1 * HH + j] * wsu[j]
                + h[(size_t)i1 * HH + j] * wsu[32 + j]
                + aggs[(size_t)i2 * HH + j] * wsu[16 + j]
                + h[(size_t)i2 * HH + j] * wsu[48 + j];
#pragma unroll
        for (int off = 8; off; off >>= 1) v += __shfl_xor(v, off, 16);
        if (j == 0) {
            float l = v + wsu[64] + wsu[65];
            out_logits[p] = l;
            float y = (float)labels[p];
            myloss = fmaxf(l, 0.f) - l * y + log1pf(expf(-fabsf(l)));
        }
    }
    if (j == 0) lred[g] = myloss;
    __syncthreads();
    if (threadIdx.x == 0) {
        float s = 0.f;
#pragma unroll
        for (int k = 0; k < 16; ++k) s += lred[k];
        atomicAdd(lacc, s);
    }
}

// K7: out[0] = loss mean
__global__ void k_final(const float* __restrict__ lacc, float* __restrict__ out, float invB) {
    out[0] = lacc[0] * invB;
}

// ---------------------------------------------------------------------------
extern "C" void kernel_launch(void* const* d_in, const int* in_sizes, int n_in,
                              void* d_out, int out_size, void* d_ws, size_t ws_size,
                              hipStream_t stream) {
    const float* x    = (const float*)d_in[0];
    const float* w1l  = (const float*)d_in[1];
    const float* b1   = (const float*)d_in[2];
    const float* w1r  = (const float*)d_in[3];
    const float* w2l  = (const float*)d_in[4];
    const float* b2v  = (const float*)d_in[5];
    const float* w2r  = (const float*)d_in[6];
    const float* wc   = (const float*)d_in[7];
    const float* bc   = (const float*)d_in[8];
    const int*   ei   = (const int*)d_in[9];
    const int*   a1   = (const int*)d_in[10];
    const int*   a2   = (const int*)d_in[11];
    const int*   lab  = (const int*)d_in[12];

    const int N = in_sizes[0] / DD;
    const int E = in_sizes[9] / 2;
    const int B = in_sizes[10];
    const int NB = (N + BW - 1) / BW;       // 782 for N=100000 (requires N < 2^20)

    const int* src = ei;
    const int* dst = ei + E;

    // workspace layout
    char* ws = (char*)d_ws;
    const size_t NH4 = (size_t)N * HH * 4;
    float* wsu     = (float*)ws;                          // 512 B
    float* y1      = (float*)(ws + 512);                  // [N,16] (reused as aggs)
    float* z1      = (float*)(ws + 512 + NH4);
    float* h       = (float*)(ws + 512 + 2 * NH4);
    int*   csr     = (int*)  (ws + 512 + 3 * NH4);        // [E] packed entries
    char*  p4      = ws + 512 + 3 * NH4 + (size_t)E * 4;
    int*   bstart  = (int*)p4;                            // [NB]
    int*   gcursor = (int*)(p4 + (size_t)NB * 4);         // [NB]
    float* invdeg  = (float*)(p4 + 2 * (size_t)NB * 4);   // [N]
    int*   bcnt    = (int*)(p4 + 2 * (size_t)NB * 4 + (size_t)N * 4);  // [NB] zeroed
    float* lacc    = (float*)(p4 + 3 * (size_t)NB * 4 + (size_t)N * 4);// [1]  zeroed

    float* aggs = y1;                 // layer-2 scaled agg reuses y1
    float* out  = (float*)d_out;      // out[0] = loss, out[1..B] = logits

    hipMemsetAsync((void*)bcnt, 0, (size_t)NB * 4 + 4, stream);

    k_prep<<<1, 128, 0, stream>>>(w2l, w2r, b2v, wc, bc, wsu);

    const int E4 = E / 4;
    const int chunks = (E4 + 2047) / 2048;   // 8192 edges per chunk

    k_bcount<<<chunks, 256, 0, stream>>>(dst, bcnt, E4, NB);
    k_bscan<<<1, 1024, 0, stream>>>(bcnt, bstart, gcursor, NB);
    k_bscatter<<<chunks, 256, 0, stream>>>(src, dst, gcursor, csr, E4, NB);

    k_xform<<<(N + 15) / 16, 256, 0, stream>>>(x, w1l, w1r, y1, z1, N);

    // layer 1: h = relu(mean(y1[nbrs]) + b1 + z1); writes invdeg
    k_bagg<<<NB, 256, 0, stream>>>(csr, bstart, bcnt, y1, z1, b1, invdeg, h, N, 0);
    // layer 2: aggs = mean(h[nbrs])  (overwrites y1)
    k_bagg<<<NB, 256, 0, stream>>>(csr, bstart, bcnt, h, nullptr, nullptr, invdeg, aggs, N, 1);

    k_pair<<<(B * 16 + 255) / 256, 256, 0, stream>>>(h, aggs, a1, a2, lab, wsu,
                                                     out + 1, lacc, B);

    k_final<<<1, 1, 0, stream>>>(lacc, out, 1.0f / (float)B);
}

// Round 5
// 252.094 us; speedup vs baseline: 2.2598x; 2.2598x over previous
//
#include <hip/hip_runtime.h>
#include <hip/hip_bf16.h>

#define DD 128    // feature dim
#define HH 16     // hidden dim
#define BW 128    // bucket width (nodes per bucket) = 1<<7
#define NBMAX 1024

// ---------------------------------------------------------------------------
// K0: collapse layer-2 + classifier into 16-dim vectors.
//   wsu[0..15]  = w2_l[j,:].wc[:128]    wsu[16..31] = w2_l[j,:].wc[128:]
//   wsu[32..47] = w2_r[j,:].wc[:128]    wsu[48..63] = w2_r[j,:].wc[128:]
//   wsu[64] = b2.wc[:128] + bc ;  wsu[65] = b2.wc[128:]
// ---------------------------------------------------------------------------
__global__ void k_prep(const float* __restrict__ w2l, const float* __restrict__ w2r,
                       const float* __restrict__ b2v, const float* __restrict__ wc,
                       const float* __restrict__ bc, float* __restrict__ wsu) {
    int t = threadIdx.x;
    if (t < 64) {
        int k = t >> 4, j = t & 15;
        const float* W = (k < 2) ? w2l : w2r;
        int off = (k & 1) * DD;
        float s = 0.f;
        for (int d = 0; d < DD; ++d) s += W[j * DD + d] * wc[off + d];
        wsu[k * 16 + j] = s;
    } else if (t == 64) {
        float s = bc[0];
        for (int d = 0; d < DD; ++d) s += b2v[d] * wc[d];
        wsu[64] = s;
    } else if (t == 65) {
        float s = 0.f;
        for (int d = 0; d < DD; ++d) s += b2v[d] * wc[DD + d];
        wsu[65] = s;
    }
}

// ---------------------------------------------------------------------------
// K1: y1 = x @ w1_l, z1 = x @ w1_r   (x: [N,128] f32 -> y1,z1: [N,16] f32)
// ---------------------------------------------------------------------------
__global__ __launch_bounds__(256) void k_xform(const float* __restrict__ x,
                                               const float* __restrict__ w1l,
                                               const float* __restrict__ w1r,
                                               float* __restrict__ y1,
                                               float* __restrict__ z1, int N) {
    __shared__ float wl[DD * HH];
    __shared__ float wr[DD * HH];
    __shared__ float xt[16 * 132];    // row stride 132 floats (33 float4)

    const int tid  = threadIdx.x;
    const int row0 = blockIdx.x * 16;

    {
        const float4* a = (const float4*)w1l;
        const float4* b = (const float4*)w1r;
        ((float4*)wl)[tid]       = a[tid];
        ((float4*)wl)[tid + 256] = a[tid + 256];
        ((float4*)wr)[tid]       = b[tid];
        ((float4*)wr)[tid + 256] = b[tid + 256];
    }
    {
        for (int k = 0; k < 2; ++k) {
            int idx = tid + k * 256;
            int r = idx >> 5, seg = idx & 31;
            if (row0 + r < N) {
                float4 v = ((const float4*)(x + (size_t)(row0 + r) * DD))[seg];
                ((float4*)xt)[r * 33 + seg] = v;
            }
        }
    }
    __syncthreads();

    const int r = tid >> 4, j = tid & 15;
    const int row = row0 + r;
    if (row >= N) return;
    float accy = 0.f, accz = 0.f;
#pragma unroll 8
    for (int d = 0; d < DD; ++d) {
        float xv = xt[r * 132 + d];
        accy += xv * wl[d * HH + j];
        accz += xv * wr[d * HH + j];
    }
    y1[(size_t)row * HH + j] = accy;
    z1[(size_t)row * HH + j] = accz;
}

// ---------------------------------------------------------------------------
// K2: per-bucket histogram. 8192 edges/block, LDS hist, one global
// atomicAdd per (block,bucket).
// ---------------------------------------------------------------------------
__global__ __launch_bounds__(256) void k_bcount(const int* __restrict__ dst,
                                                int* __restrict__ bcnt,
                                                int E4, int NB) {
    __shared__ int hist[NBMAX];
    for (int i = threadIdx.x; i < NB; i += 256) hist[i] = 0;
    __syncthreads();
    int base = blockIdx.x * 2048;
#pragma unroll
    for (int k = 0; k < 8; ++k) {
        int i4 = base + k * 256 + threadIdx.x;
        if (i4 < E4) {
            int4 d = ((const int4*)dst)[i4];
            atomicAdd(&hist[d.x >> 7], 1);
            atomicAdd(&hist[d.y >> 7], 1);
            atomicAdd(&hist[d.z >> 7], 1);
            atomicAdd(&hist[d.w >> 7], 1);
        }
    }
    __syncthreads();
    for (int i = threadIdx.x; i < NB; i += 256) {
        int h = hist[i];
        if (h) atomicAdd(&bcnt[i], h);
    }
}

// ---------------------------------------------------------------------------
// K3: exclusive scan over NB bucket counts -> bstart (+[NB]=E), gcursor;
// also nodestart[N] = E. Single block of 1024.
// ---------------------------------------------------------------------------
__global__ __launch_bounds__(1024) void k_bscan(const int* __restrict__ bcnt,
                                                int* __restrict__ bstart,
                                                int* __restrict__ gcursor,
                                                int* __restrict__ nodestart,
                                                int NB, int N, int E) {
    __shared__ int sa[1024];
    __shared__ int sb[1024];
    int t = threadIdx.x;
    int v = (t < NB) ? bcnt[t] : 0;
    sa[t] = v;
    __syncthreads();
    int* cur = sa;
    int* nxt = sb;
    for (int off = 1; off < 1024; off <<= 1) {
        int xv = cur[t];
        if (t >= off) xv += cur[t - off];
        nxt[t] = xv;
        __syncthreads();
        int* tmp = cur; cur = nxt; nxt = tmp;
    }
    if (t < NB) {
        int excl = cur[t] - v;
        bstart[t] = excl;
        gcursor[t] = excl;
    }
    if (t == 0) {
        bstart[NB] = cur[1023];
        nodestart[N] = E;
    }
}

// ---------------------------------------------------------------------------
// K4: bucketed scatter. Per chunk: LDS hist -> bulk range reservation ->
// packed entries (local<<20 | src). Writes land in ~contiguous per-bucket
// ranges -> no 16x line amplification.
// ---------------------------------------------------------------------------
__global__ __launch_bounds__(256) void k_bscatter(const int* __restrict__ src,
                                                  const int* __restrict__ dst,
                                                  int* __restrict__ gcursor,
                                                  int* __restrict__ packed,
                                                  int E4, int NB) {
    __shared__ int hist[NBMAX];
    __shared__ int cur[NBMAX];
    for (int i = threadIdx.x; i < NB; i += 256) hist[i] = 0;
    __syncthreads();
    int base = blockIdx.x * 2048;
    int4 dreg[8];
#pragma unroll
    for (int k = 0; k < 8; ++k) {
        int i4 = base + k * 256 + threadIdx.x;
        if (i4 < E4) {
            int4 d = ((const int4*)dst)[i4];
            dreg[k] = d;
            atomicAdd(&hist[d.x >> 7], 1);
            atomicAdd(&hist[d.y >> 7], 1);
            atomicAdd(&hist[d.z >> 7], 1);
            atomicAdd(&hist[d.w >> 7], 1);
        }
    }
    __syncthreads();
    for (int i = threadIdx.x; i < NB; i += 256) {
        int h = hist[i];
        cur[i] = h ? atomicAdd(&gcursor[i], h) : 0;
    }
    __syncthreads();
#pragma unroll
    for (int k = 0; k < 8; ++k) {
        int i4 = base + k * 256 + threadIdx.x;
        if (i4 < E4) {
            int4 s = ((const int4*)src)[i4];
            int4 d = dreg[k];
            int p;
            p = atomicAdd(&cur[d.x >> 7], 1); packed[p] = ((d.x & 127) << 20) | s.x;
            p = atomicAdd(&cur[d.y >> 7], 1); packed[p] = ((d.y & 127) << 20) | s.y;
            p = atomicAdd(&cur[d.z >> 7], 1); packed[p] = ((d.z & 127) << 20) | s.z;
            p = atomicAdd(&cur[d.w >> 7], 1); packed[p] = ((d.w & 127) << 20) | s.w;
        }
    }
}

// ---------------------------------------------------------------------------
// K5: bucket-local counting sort -> per-node CSR + nodestart.
// One block per bucket; all reads/writes within the bucket's contiguous
// global range (streaming; no line amplification).
// ---------------------------------------------------------------------------
__global__ __launch_bounds__(256) void k_sort(const int* __restrict__ packed,
                                              const int* __restrict__ bstart,
                                              int* __restrict__ nodestart,
                                              int* __restrict__ csr, int N) {
    __shared__ int hist[BW];
    __shared__ int curs[BW];
    __shared__ int wtot;
    int tid = threadIdx.x;
    int b = blockIdx.x;
    int st = bstart[b], en = bstart[b + 1], cnt = en - st;

    if (tid < BW) hist[tid] = 0;
    __syncthreads();
    for (int i = tid; i < cnt; i += 256)
        atomicAdd(&hist[packed[st + i] >> 20], 1);
    __syncthreads();

    int v = 0, excl = 0;
    if (tid < BW) {                       // threads 0..127 = waves 0,1
        int lane = tid & 63;
        v = hist[tid];
        int s = v;
#pragma unroll
        for (int off = 1; off < 64; off <<= 1) {
            int u = __shfl_up(s, off, 64);
            if (lane >= off) s += u;
        }
        excl = s - v;
        if (tid == 63) wtot = s;          // total of locals 0..63
    }
    __syncthreads();
    if (tid < BW) {
        if (tid >= 64) excl += wtot;
        curs[tid] = excl;
        int node = (b << 7) + tid;
        if (node < N) nodestart[node] = st + excl;
    }
    __syncthreads();
    for (int i = tid; i < cnt; i += 256) {
        int e = packed[st + i];
        int p = atomicAdd(&curs[e >> 20], 1);
        csr[st + p] = e & 0xFFFFF;
    }
}

// ---------------------------------------------------------------------------
// K6: node-pull segment mean. 4 lanes per node; lane seg owns a float4
// column. 4-edge unroll -> 4 independent float4 gathers in flight/thread.
// mode 0: out = relu(sum/deg + b1 + z1)     mode 1: out = sum/deg
// ---------------------------------------------------------------------------
__global__ __launch_bounds__(256) void k_agg(const int* __restrict__ csr,
                                             const int* __restrict__ nodestart,
                                             const float* __restrict__ feat,
                                             const float* __restrict__ z1,
                                             const float* __restrict__ b1,
                                             float* __restrict__ outv,
                                             int N, int mode) {
    int t = blockIdx.x * 256 + threadIdx.x;
    int node = t >> 2, seg = t & 3;
    if (node >= N) return;
    int st = nodestart[node], en = nodestart[node + 1];
    const float4* f4 = (const float4*)feat;

    float ax = 0.f, ay = 0.f, az = 0.f, aw = 0.f;
    int k = st;
    for (; k + 4 <= en; k += 4) {
        int s0 = csr[k], s1 = csr[k + 1], s2 = csr[k + 2], s3 = csr[k + 3];
        float4 a = f4[(size_t)(s0 * 4 + seg)];
        float4 b = f4[(size_t)(s1 * 4 + seg)];
        float4 c = f4[(size_t)(s2 * 4 + seg)];
        float4 d = f4[(size_t)(s3 * 4 + seg)];
        ax += (a.x + b.x) + (c.x + d.x);
        ay += (a.y + b.y) + (c.y + d.y);
        az += (a.z + b.z) + (c.z + d.z);
        aw += (a.w + b.w) + (c.w + d.w);
    }
    for (; k < en; ++k) {
        float4 a = f4[(size_t)(csr[k] * 4 + seg)];
        ax += a.x; ay += a.y; az += a.z; aw += a.w;
    }
    float inv = 1.f / fmaxf((float)(en - st), 1.f);
    size_t o = (size_t)node * 4 + seg;
    float4 r;
    if (mode == 0) {
        float4 z = ((const float4*)z1)[o];
        float4 bb = ((const float4*)b1)[seg];
        r.x = fmaxf(ax * inv + bb.x + z.x, 0.f);
        r.y = fmaxf(ay * inv + bb.y + z.y, 0.f);
        r.z = fmaxf(az * inv + bb.z + z.z, 0.f);
        r.w = fmaxf(aw * inv + bb.w + z.w, 0.f);
    } else {
        r.x = ax * inv; r.y = ay * inv; r.z = az * inv; r.w = aw * inv;
    }
    ((float4*)outv)[o] = r;
}

// ---------------------------------------------------------------------------
// K7: per-pair logits + BCE partial sums. 16 lanes per pair.
// ---------------------------------------------------------------------------
__global__ __launch_bounds__(256) void k_pair(const float* __restrict__ h,
                                              const float* __restrict__ aggs,
                                              const int* __restrict__ a1,
                                              const int* __restrict__ a2,
                                              const int* __restrict__ labels,
                                              const float* __restrict__ wsu,
                                              float* __restrict__ out_logits,
                                              float* __restrict__ lacc, int B) {
    __shared__ float lred[16];
    int t = blockIdx.x * 256 + threadIdx.x;
    int p = t >> 4, j = t & 15;
    int g = threadIdx.x >> 4;

    float myloss = 0.f;
    if (p < B) {
        int i1 = a1[p], i2 = a2[p];
        float v = aggs[(size_t)i1 * HH + j] * wsu[j]
                + h[(size_t)i1 * HH + j] * wsu[32 + j]
                + aggs[(size_t)i2 * HH + j] * wsu[16 + j]
                + h[(size_t)i2 * HH + j] * wsu[48 + j];
#pragma unroll
        for (int off = 8; off; off >>= 1) v += __shfl_xor(v, off, 16);
        if (j == 0) {
            float l = v + wsu[64] + wsu[65];
            out_logits[p] = l;
            float y = (float)labels[p];
            myloss = fmaxf(l, 0.f) - l * y + log1pf(expf(-fabsf(l)));
        }
    }
    if (j == 0) lred[g] = myloss;
    __syncthreads();
    if (threadIdx.x == 0) {
        float s = 0.f;
#pragma unroll
        for (int k = 0; k < 16; ++k) s += lred[k];
        atomicAdd(lacc, s);
    }
}

// K8: out[0] = loss mean
__global__ void k_final(const float* __restrict__ lacc, float* __restrict__ out, float invB) {
    out[0] = lacc[0] * invB;
}

// ---------------------------------------------------------------------------
extern "C" void kernel_launch(void* const* d_in, const int* in_sizes, int n_in,
                              void* d_out, int out_size, void* d_ws, size_t ws_size,
                              hipStream_t stream) {
    const float* x    = (const float*)d_in[0];
    const float* w1l  = (const float*)d_in[1];
    const float* b1   = (const float*)d_in[2];
    const float* w1r  = (const float*)d_in[3];
    const float* w2l  = (const float*)d_in[4];
    const float* b2v  = (const float*)d_in[5];
    const float* w2r  = (const float*)d_in[6];
    const float* wc   = (const float*)d_in[7];
    const float* bc   = (const float*)d_in[8];
    const int*   ei   = (const int*)d_in[9];
    const int*   a1   = (const int*)d_in[10];
    const int*   a2   = (const int*)d_in[11];
    const int*   lab  = (const int*)d_in[12];

    const int N = in_sizes[0] / DD;
    const int E = in_sizes[9] / 2;
    const int B = in_sizes[10];
    const int NB = (N + BW - 1) / BW;       // 782 for N=100000 (needs N < 2^20)

    const int* src = ei;
    const int* dst = ei + E;

    // workspace layout
    char* ws = (char*)d_ws;
    const size_t NH4 = (size_t)N * HH * 4;
    float* wsu     = (float*)ws;                             // 512 B
    float* y1      = (float*)(ws + 512);                     // [N,16] (reused as aggs)
    float* z1      = (float*)(ws + 512 + NH4);
    float* h       = (float*)(ws + 512 + 2 * NH4);
    int*   packed  = (int*)  (ws + 512 + 3 * NH4);           // [E]
    int*   csr     = (int*)  (ws + 512 + 3 * NH4 + (size_t)E * 4);  // [E]
    char*  p4      = ws + 512 + 3 * NH4 + 2 * (size_t)E * 4;
    int*   nodest  = (int*)p4;                               // [N+1]
    int*   bstart  = (int*)(p4 + ((size_t)N + 1) * 4);       // [NB+1]
    int*   gcursor = (int*)(p4 + ((size_t)N + 1) * 4 + ((size_t)NB + 1) * 4);  // [NB]
    int*   bcnt    = (int*)(p4 + ((size_t)N + 1) * 4 + (2 * (size_t)NB + 1) * 4); // [NB] zeroed
    float* lacc    = (float*)(p4 + ((size_t)N + 1) * 4 + (3 * (size_t)NB + 1) * 4);// [1] zeroed

    float* aggs = y1;                 // layer-2 scaled agg reuses y1
    float* out  = (float*)d_out;      // out[0] = loss, out[1..B] = logits

    hipMemsetAsync((void*)bcnt, 0, (size_t)NB * 4 + 4, stream);

    k_prep<<<1, 128, 0, stream>>>(w2l, w2r, b2v, wc, bc, wsu);

    const int E4 = E / 4;
    const int chunks = (E4 + 2047) / 2048;   // 8192 edges per chunk

    k_bcount<<<chunks, 256, 0, stream>>>(dst, bcnt, E4, NB);
    k_bscan<<<1, 1024, 0, stream>>>(bcnt, bstart, gcursor, nodest, NB, N, E);
    k_bscatter<<<chunks, 256, 0, stream>>>(src, dst, gcursor, packed, E4, NB);
    k_sort<<<NB, 256, 0, stream>>>(packed, bstart, nodest, csr, N);

    k_xform<<<(N + 15) / 16, 256, 0, stream>>>(x, w1l, w1r, y1, z1, N);

    // layer 1: h = relu(mean(y1[nbrs]) + b1 + z1)
    k_agg<<<((N * 4) + 255) / 256, 256, 0, stream>>>(csr, nodest, y1, z1, b1, h, N, 0);
    // layer 2: aggs = mean(h[nbrs])  (overwrites y1)
    k_agg<<<((N * 4) + 255) / 256, 256, 0, stream>>>(csr, nodest, h, nullptr, nullptr, aggs, N, 1);

    k_pair<<<(B * 16 + 255) / 256, 256, 0, stream>>>(h, aggs, a1, a2, lab, wsu,
                                                     out + 1, lacc, B);

    k_final<<<1, 1, 0, stream>>>(lacc, out, 1.0f / (float)B);
}

// Round 6
// 239.995 us; speedup vs baseline: 2.3737x; 1.0504x over previous
//
#include <hip/hip_runtime.h>
#include <hip/hip_bf16.h>

#define DD 128    // feature dim
#define HH 16     // hidden dim
#define BW 128    // bucket width (nodes per bucket) = 1<<7
#define NBMAX 1024

// ---------------------------------------------------------------------------
// K0: collapse layer-2 + classifier into 16-dim vectors.
//   wsu[0..15]  = w2_l[j,:].wc[:128]    wsu[16..31] = w2_l[j,:].wc[128:]
//   wsu[32..47] = w2_r[j,:].wc[:128]    wsu[48..63] = w2_r[j,:].wc[128:]
//   wsu[64] = b2.wc[:128] + bc ;  wsu[65] = b2.wc[128:]
// ---------------------------------------------------------------------------
__global__ void k_prep(const float* __restrict__ w2l, const float* __restrict__ w2r,
                       const float* __restrict__ b2v, const float* __restrict__ wc,
                       const float* __restrict__ bc, float* __restrict__ wsu) {
    int t = threadIdx.x;
    if (t < 64) {
        int k = t >> 4, j = t & 15;
        const float* W = (k < 2) ? w2l : w2r;
        int off = (k & 1) * DD;
        float s = 0.f;
        for (int d = 0; d < DD; ++d) s += W[j * DD + d] * wc[off + d];
        wsu[k * 16 + j] = s;
    } else if (t == 64) {
        float s = bc[0];
        for (int d = 0; d < DD; ++d) s += b2v[d] * wc[d];
        wsu[64] = s;
    } else if (t == 65) {
        float s = 0.f;
        for (int d = 0; d < DD; ++d) s += b2v[d] * wc[DD + d];
        wsu[65] = s;
    }
}

// ---------------------------------------------------------------------------
// K1: y1 = x @ w1_l, z1 = x @ w1_r   (x: [N,128] f32 -> y1,z1: [N,16] f32)
// 64 rows/block; 4 lanes/row; each lane owns 8 outputs (f4 of y1 + f4 of z1).
// Per d: 1 scalar xt read (2-way alias, free) + 2 ds_read_b128 weight reads
// (4 distinct addrs/wave -> broadcast) + 8 FMAs.
// ---------------------------------------------------------------------------
__global__ __launch_bounds__(256) void k_xform(const float* __restrict__ x,
                                               const float* __restrict__ w1l,
                                               const float* __restrict__ w1r,
                                               float* __restrict__ y1,
                                               float* __restrict__ z1, int N) {
    __shared__ float wl[DD * HH];     // 8 KB, layout [d*16 + j]
    __shared__ float wr[DD * HH];     // 8 KB
    __shared__ float xt[64 * 132];    // 33.8 KB, row stride 132 f (33 f4)

    const int tid  = threadIdx.x;
    const int row0 = blockIdx.x * 64;

    {
        const float4* a = (const float4*)w1l;
        const float4* b = (const float4*)w1r;
        ((float4*)wl)[tid]       = a[tid];
        ((float4*)wl)[tid + 256] = a[tid + 256];
        ((float4*)wr)[tid]       = b[tid];
        ((float4*)wr)[tid + 256] = b[tid + 256];
    }
#pragma unroll
    for (int k = 0; k < 8; ++k) {     // 64 rows x 32 f4 = 2048 f4, 8/thread
        int idx = tid + k * 256;
        int r = idx >> 5, c = idx & 31;
        if (row0 + r < N)
            ((float4*)xt)[r * 33 + c] = ((const float4*)(x + (size_t)(row0 + r) * DD))[c];
    }
    __syncthreads();

    const int r = tid >> 2, seg = tid & 3;
    const int row = row0 + r;
    if (row >= N) return;
    float4 accy = {0.f, 0.f, 0.f, 0.f};
    float4 accz = {0.f, 0.f, 0.f, 0.f};
    const float* xrow = &xt[r * 132];
#pragma unroll 8
    for (int d = 0; d < DD; ++d) {
        float xv = xrow[d];
        float4 wl4 = *(const float4*)&wl[d * HH + seg * 4];
        float4 wr4 = *(const float4*)&wr[d * HH + seg * 4];
        accy.x += xv * wl4.x; accy.y += xv * wl4.y;
        accy.z += xv * wl4.z; accy.w += xv * wl4.w;
        accz.x += xv * wr4.x; accz.y += xv * wr4.y;
        accz.z += xv * wr4.z; accz.w += xv * wr4.w;
    }
    ((float4*)y1)[(size_t)row * 4 + seg] = accy;
    ((float4*)z1)[(size_t)row * 4 + seg] = accz;
}

// ---------------------------------------------------------------------------
// K2: per-bucket histogram. 8192 edges/block, LDS hist, one global
// atomicAdd per (block,bucket).
// ---------------------------------------------------------------------------
__global__ __launch_bounds__(256) void k_bcount(const int* __restrict__ dst,
                                                int* __restrict__ bcnt,
                                                int E4, int NB) {
    __shared__ int hist[NBMAX];
    for (int i = threadIdx.x; i < NB; i += 256) hist[i] = 0;
    __syncthreads();
    int base = blockIdx.x * 2048;
#pragma unroll
    for (int k = 0; k < 8; ++k) {
        int i4 = base + k * 256 + threadIdx.x;
        if (i4 < E4) {
            int4 d = ((const int4*)dst)[i4];
            atomicAdd(&hist[d.x >> 7], 1);
            atomicAdd(&hist[d.y >> 7], 1);
            atomicAdd(&hist[d.z >> 7], 1);
            atomicAdd(&hist[d.w >> 7], 1);
        }
    }
    __syncthreads();
    for (int i = threadIdx.x; i < NB; i += 256) {
        int h = hist[i];
        if (h) atomicAdd(&bcnt[i], h);
    }
}

// ---------------------------------------------------------------------------
// K3: exclusive scan over NB bucket counts -> bstart (+[NB]=E), gcursor;
// also nodestart[N] = E. Single block of 1024.
// ---------------------------------------------------------------------------
__global__ __launch_bounds__(1024) void k_bscan(const int* __restrict__ bcnt,
                                                int* __restrict__ bstart,
                                                int* __restrict__ gcursor,
                                                int* __restrict__ nodestart,
                                                int NB, int N, int E) {
    __shared__ int sa[1024];
    __shared__ int sb[1024];
    int t = threadIdx.x;
    int v = (t < NB) ? bcnt[t] : 0;
    sa[t] = v;
    __syncthreads();
    int* cur = sa;
    int* nxt = sb;
    for (int off = 1; off < 1024; off <<= 1) {
        int xv = cur[t];
        if (t >= off) xv += cur[t - off];
        nxt[t] = xv;
        __syncthreads();
        int* tmp = cur; cur = nxt; nxt = tmp;
    }
    if (t < NB) {
        int excl = cur[t] - v;
        bstart[t] = excl;
        gcursor[t] = excl;
    }
    if (t == 0) {
        bstart[NB] = cur[1023];
        nodestart[N] = E;
    }
}

// ---------------------------------------------------------------------------
// K4: bucketed scatter. Per chunk: LDS hist -> bulk range reservation ->
// packed entries (local<<20 | src). Writes land in ~contiguous per-bucket
// ranges -> no 16x line amplification.
// ---------------------------------------------------------------------------
__global__ __launch_bounds__(256) void k_bscatter(const int* __restrict__ src,
                                                  const int* __restrict__ dst,
                                                  int* __restrict__ gcursor,
                                                  int* __restrict__ packed,
                                                  int E4, int NB) {
    __shared__ int hist[NBMAX];
    __shared__ int cur[NBMAX];
    for (int i = threadIdx.x; i < NB; i += 256) hist[i] = 0;
    __syncthreads();
    int base = blockIdx.x * 2048;
    int4 dreg[8];
#pragma unroll
    for (int k = 0; k < 8; ++k) {
        int i4 = base + k * 256 + threadIdx.x;
        if (i4 < E4) {
            int4 d = ((const int4*)dst)[i4];
            dreg[k] = d;
            atomicAdd(&hist[d.x >> 7], 1);
            atomicAdd(&hist[d.y >> 7], 1);
            atomicAdd(&hist[d.z >> 7], 1);
            atomicAdd(&hist[d.w >> 7], 1);
        }
    }
    __syncthreads();
    for (int i = threadIdx.x; i < NB; i += 256) {
        int h = hist[i];
        cur[i] = h ? atomicAdd(&gcursor[i], h) : 0;
    }
    __syncthreads();
#pragma unroll
    for (int k = 0; k < 8; ++k) {
        int i4 = base + k * 256 + threadIdx.x;
        if (i4 < E4) {
            int4 s = ((const int4*)src)[i4];
            int4 d = dreg[k];
            int p;
            p = atomicAdd(&cur[d.x >> 7], 1); packed[p] = ((d.x & 127) << 20) | s.x;
            p = atomicAdd(&cur[d.y >> 7], 1); packed[p] = ((d.y & 127) << 20) | s.y;
            p = atomicAdd(&cur[d.z >> 7], 1); packed[p] = ((d.z & 127) << 20) | s.z;
            p = atomicAdd(&cur[d.w >> 7], 1); packed[p] = ((d.w & 127) << 20) | s.w;
        }
    }
}

// ---------------------------------------------------------------------------
// K5: bucket-local counting sort -> per-node CSR + nodestart.
// One block per bucket; all reads/writes within the bucket's contiguous
// global range (streaming; no line amplification).
// ---------------------------------------------------------------------------
__global__ __launch_bounds__(256) void k_sort(const int* __restrict__ packed,
                                              const int* __restrict__ bstart,
                                              int* __restrict__ nodestart,
                                              int* __restrict__ csr, int N) {
    __shared__ int hist[BW];
    __shared__ int curs[BW];
    __shared__ int wtot;
    int tid = threadIdx.x;
    int b = blockIdx.x;
    int st = bstart[b], en = bstart[b + 1], cnt = en - st;

    if (tid < BW) hist[tid] = 0;
    __syncthreads();
    for (int i = tid; i < cnt; i += 256)
        atomicAdd(&hist[packed[st + i] >> 20], 1);
    __syncthreads();

    int v = 0, excl = 0;
    if (tid < BW) {                       // threads 0..127 = waves 0,1
        int lane = tid & 63;
        v = hist[tid];
        int s = v;
#pragma unroll
        for (int off = 1; off < 64; off <<= 1) {
            int u = __shfl_up(s, off, 64);
            if (lane >= off) s += u;
        }
        excl = s - v;
        if (tid == 63) wtot = s;          // total of locals 0..63
    }
    __syncthreads();
    if (tid < BW) {
        if (tid >= 64) excl += wtot;
        curs[tid] = excl;
        int node = (b << 7) + tid;
        if (node < N) nodestart[node] = st + excl;
    }
    __syncthreads();
    for (int i = tid; i < cnt; i += 256) {
        int e = packed[st + i];
        int p = atomicAdd(&curs[e >> 20], 1);
        csr[st + p] = e & 0xFFFFF;
    }
}

// ---------------------------------------------------------------------------
// K6: node-pull segment mean. 4 lanes per node; lane seg owns a float4
// column. 4-edge unroll -> 4 independent float4 gathers in flight/thread.
// mode 0: out = relu(sum/deg + b1 + z1)     mode 1: out = sum/deg
// ---------------------------------------------------------------------------
__global__ __launch_bounds__(256) void k_agg(const int* __restrict__ csr,
                                             const int* __restrict__ nodestart,
                                             const float* __restrict__ feat,
                                             const float* __restrict__ z1,
                                             const float* __restrict__ b1,
                                             float* __restrict__ outv,
                                             int N, int mode) {
    int t = blockIdx.x * 256 + threadIdx.x;
    int node = t >> 2, seg = t & 3;
    if (node >= N) return;
    int st = nodestart[node], en = nodestart[node + 1];
    const float4* f4 = (const float4*)feat;

    float ax = 0.f, ay = 0.f, az = 0.f, aw = 0.f;
    int k = st;
    for (; k + 4 <= en; k += 4) {
        int s0 = csr[k], s1 = csr[k + 1], s2 = csr[k + 2], s3 = csr[k + 3];
        float4 a = f4[(size_t)(s0 * 4 + seg)];
        float4 b = f4[(size_t)(s1 * 4 + seg)];
        float4 c = f4[(size_t)(s2 * 4 + seg)];
        float4 d = f4[(size_t)(s3 * 4 + seg)];
        ax += (a.x + b.x) + (c.x + d.x);
        ay += (a.y + b.y) + (c.y + d.y);
        az += (a.z + b.z) + (c.z + d.z);
        aw += (a.w + b.w) + (c.w + d.w);
    }
    for (; k < en; ++k) {
        float4 a = f4[(size_t)(csr[k] * 4 + seg)];
        ax += a.x; ay += a.y; az += a.z; aw += a.w;
    }
    float inv = 1.f / fmaxf((float)(en - st), 1.f);
    size_t o = (size_t)node * 4 + seg;
    float4 r;
    if (mode == 0) {
        float4 z = ((const float4*)z1)[o];
        float4 bb = ((const float4*)b1)[seg];
        r.x = fmaxf(ax * inv + bb.x + z.x, 0.f);
        r.y = fmaxf(ay * inv + bb.y + z.y, 0.f);
        r.z = fmaxf(az * inv + bb.z + z.z, 0.f);
        r.w = fmaxf(aw * inv + bb.w + z.w, 0.f);
    } else {
        r.x = ax * inv; r.y = ay * inv; r.z = az * inv; r.w = aw * inv;
    }
    ((float4*)outv)[o] = r;
}

// ---------------------------------------------------------------------------
// K7: per-pair logits + BCE partial sums. 16 lanes per pair.
// ---------------------------------------------------------------------------
__global__ __launch_bounds__(256) void k_pair(const float* __restrict__ h,
                                              const float* __restrict__ aggs,
                                              const int* __restrict__ a1,
                                              const int* __restrict__ a2,
                                              const int* __restrict__ labels,
                                              const float* __restrict__ wsu,
                                              float* __restrict__ out_logits,
                                              float* __restrict__ lacc, int B) {
    __shared__ float lred[16];
    int t = blockIdx.x * 256 + threadIdx.x;
    int p = t >> 4, j = t & 15;
    int g = threadIdx.x >> 4;

    float myloss = 0.f;
    if (p < B) {
        int i1 = a1[p], i2 = a2[p];
        float v = aggs[(size_t)i1 * HH + j] * wsu[j]
                + h[(size_t)i1 * HH + j] * wsu[32 + j]
                + aggs[(size_t)i2 * HH + j] * wsu[16 + j]
                + h[(size_t)i2 * HH + j] * wsu[48 + j];
#pragma unroll
        for (int off = 8; off; off >>= 1) v += __shfl_xor(v, off, 16);
        if (j == 0) {
            float l = v + wsu[64] + wsu[65];
            out_logits[p] = l;
            float y = (float)labels[p];
            myloss = fmaxf(l, 0.f) - l * y + log1pf(expf(-fabsf(l)));
        }
    }
    if (j == 0) lred[g] = myloss;
    __syncthreads();
    if (threadIdx.x == 0) {
        float s = 0.f;
#pragma unroll
        for (int k = 0; k < 16; ++k) s += lred[k];
        atomicAdd(lacc, s);
    }
}

// K8: out[0] = loss mean
__global__ void k_final(const float* __restrict__ lacc, float* __restrict__ out, float invB) {
    out[0] = lacc[0] * invB;
}

// ---------------------------------------------------------------------------
extern "C" void kernel_launch(void* const* d_in, const int* in_sizes, int n_in,
                              void* d_out, int out_size, void* d_ws, size_t ws_size,
                              hipStream_t stream) {
    const float* x    = (const float*)d_in[0];
    const float* w1l  = (const float*)d_in[1];
    const float* b1   = (const float*)d_in[2];
    const float* w1r  = (const float*)d_in[3];
    const float* w2l  = (const float*)d_in[4];
    const float* b2v  = (const float*)d_in[5];
    const float* w2r  = (const float*)d_in[6];
    const float* wc   = (const float*)d_in[7];
    const float* bc   = (const float*)d_in[8];
    const int*   ei   = (const int*)d_in[9];
    const int*   a1   = (const int*)d_in[10];
    const int*   a2   = (const int*)d_in[11];
    const int*   lab  = (const int*)d_in[12];

    const int N = in_sizes[0] / DD;
    const int E = in_sizes[9] / 2;
    const int B = in_sizes[10];
    const int NB = (N + BW - 1) / BW;       // 782 for N=100000 (needs N < 2^20)

    const int* src = ei;
    const int* dst = ei + E;

    // workspace layout
    char* ws = (char*)d_ws;
    const size_t NH4 = (size_t)N * HH * 4;
    float* wsu     = (float*)ws;                             // 512 B
    float* y1      = (float*)(ws + 512);                     // [N,16] (reused as aggs)
    float* z1      = (float*)(ws + 512 + NH4);
    float* h       = (float*)(ws + 512 + 2 * NH4);
    int*   packed  = (int*)  (ws + 512 + 3 * NH4);           // [E]
    int*   csr     = (int*)  (ws + 512 + 3 * NH4 + (size_t)E * 4);  // [E]
    char*  p4      = ws + 512 + 3 * NH4 + 2 * (size_t)E * 4;
    int*   nodest  = (int*)p4;                               // [N+1]
    int*   bstart  = (int*)(p4 + ((size_t)N + 1) * 4);       // [NB+1]
    int*   gcursor = (int*)(p4 + ((size_t)N + 1) * 4 + ((size_t)NB + 1) * 4);  // [NB]
    int*   bcnt    = (int*)(p4 + ((size_t)N + 1) * 4 + (2 * (size_t)NB + 1) * 4); // [NB] zeroed
    float* lacc    = (float*)(p4 + ((size_t)N + 1) * 4 + (3 * (size_t)NB + 1) * 4);// [1] zeroed

    float* aggs = y1;                 // layer-2 scaled agg reuses y1
    float* out  = (float*)d_out;      // out[0] = loss, out[1..B] = logits

    hipMemsetAsync((void*)bcnt, 0, (size_t)NB * 4 + 4, stream);

    k_prep<<<1, 128, 0, stream>>>(w2l, w2r, b2v, wc, bc, wsu);

    const int E4 = E / 4;
    const int chunks = (E4 + 2047) / 2048;   // 8192 edges per chunk

    k_bcount<<<chunks, 256, 0, stream>>>(dst, bcnt, E4, NB);
    k_bscan<<<1, 1024, 0, stream>>>(bcnt, bstart, gcursor, nodest, NB, N, E);
    k_bscatter<<<chunks, 256, 0, stream>>>(src, dst, gcursor, packed, E4, NB);
    k_sort<<<NB, 256, 0, stream>>>(packed, bstart, nodest, csr, N);

    k_xform<<<(N + 63) / 64, 256, 0, stream>>>(x, w1l, w1r, y1, z1, N);

    // layer 1: h = relu(mean(y1[nbrs]) + b1 + z1)
    k_agg<<<((N * 4) + 255) / 256, 256, 0, stream>>>(csr, nodest, y1, z1, b1, h, N, 0);
    // layer 2: aggs = mean(h[nbrs])  (overwrites y1)
    k_agg<<<((N * 4) + 255) / 256, 256, 0, stream>>>(csr, nodest, h, nullptr, nullptr, aggs, N, 1);

    k_pair<<<(B * 16 + 255) / 256, 256, 0, stream>>>(h, aggs, a1, a2, lab, wsu,
                                                     out + 1, lacc, B);

    k_final<<<1, 1, 0, stream>>>(lacc, out, 1.0f / (float)B);
}

// Round 7
// 227.608 us; speedup vs baseline: 2.5029x; 1.0544x over previous
//
#include <hip/hip_runtime.h>
#include <hip/hip_bf16.h>

#define DD 128    // feature dim
#define HH 16     // hidden dim
#define BW 128    // bucket width (nodes per bucket) = 1<<7
#define NBMAX 1024
#define SORT_CAP 12288   // LDS staging cap for k_sort (48 KB)

// ---------------------------------------------------------------------------
// K1: fused bucket histogram (blocks 0..chunks-1) + classifier-collapse prep
// (block == chunks).
//   wsu[0..15]  = w2_l[j,:].wc[:128]    wsu[16..31] = w2_l[j,:].wc[128:]
//   wsu[32..47] = w2_r[j,:].wc[:128]    wsu[48..63] = w2_r[j,:].wc[128:]
//   wsu[64] = b2.wc[:128] + bc ;  wsu[65] = b2.wc[128:]
// ---------------------------------------------------------------------------
__global__ __launch_bounds__(256) void k_bcount(const int* __restrict__ dst,
                                                int* __restrict__ bcnt,
                                                int E4, int NB, int chunks,
                                                const float* __restrict__ w2l,
                                                const float* __restrict__ w2r,
                                                const float* __restrict__ b2v,
                                                const float* __restrict__ wc,
                                                const float* __restrict__ bc,
                                                float* __restrict__ wsu) {
    if (blockIdx.x == (unsigned)chunks) {       // prep block
        int t = threadIdx.x;
        if (t < 64) {
            int k = t >> 4, j = t & 15;
            const float* W = (k < 2) ? w2l : w2r;
            int off = (k & 1) * DD;
            float s = 0.f;
            for (int d = 0; d < DD; ++d) s += W[j * DD + d] * wc[off + d];
            wsu[k * 16 + j] = s;
        } else if (t == 64) {
            float s = bc[0];
            for (int d = 0; d < DD; ++d) s += b2v[d] * wc[d];
            wsu[64] = s;
        } else if (t == 65) {
            float s = 0.f;
            for (int d = 0; d < DD; ++d) s += b2v[d] * wc[DD + d];
            wsu[65] = s;
        }
        return;
    }
    __shared__ int hist[NBMAX];
    for (int i = threadIdx.x; i < NB; i += 256) hist[i] = 0;
    __syncthreads();
    int base = blockIdx.x * 2048;
#pragma unroll
    for (int k = 0; k < 8; ++k) {
        int i4 = base + k * 256 + threadIdx.x;
        if (i4 < E4) {
            int4 d = ((const int4*)dst)[i4];
            atomicAdd(&hist[d.x >> 7], 1);
            atomicAdd(&hist[d.y >> 7], 1);
            atomicAdd(&hist[d.z >> 7], 1);
            atomicAdd(&hist[d.w >> 7], 1);
        }
    }
    __syncthreads();
    for (int i = threadIdx.x; i < NB; i += 256) {
        int h = hist[i];
        if (h) atomicAdd(&bcnt[i], h);
    }
}

// ---------------------------------------------------------------------------
// K2: exclusive scan over NB bucket counts -> bstart (+[NB]=E), gcursor;
// also nodestart[N] = E. Single block of 1024.
// ---------------------------------------------------------------------------
__global__ __launch_bounds__(1024) void k_bscan(const int* __restrict__ bcnt,
                                                int* __restrict__ bstart,
                                                int* __restrict__ gcursor,
                                                int* __restrict__ nodestart,
                                                int NB, int N, int E) {
    __shared__ int sa[1024];
    __shared__ int sb[1024];
    int t = threadIdx.x;
    int v = (t < NB) ? bcnt[t] : 0;
    sa[t] = v;
    __syncthreads();
    int* cur = sa;
    int* nxt = sb;
    for (int off = 1; off < 1024; off <<= 1) {
        int xv = cur[t];
        if (t >= off) xv += cur[t - off];
        nxt[t] = xv;
        __syncthreads();
        int* tmp = cur; cur = nxt; nxt = tmp;
    }
    if (t < NB) {
        int excl = cur[t] - v;
        bstart[t] = excl;
        gcursor[t] = excl;
    }
    if (t == 0) {
        bstart[NB] = cur[1023];
        nodestart[N] = E;
    }
}

// ---------------------------------------------------------------------------
// K3: bucketed scatter. Per chunk: LDS hist -> bulk range reservation ->
// packed entries (local<<20 | src). Writes land in ~contiguous per-bucket
// ranges -> no 16x line amplification.
// ---------------------------------------------------------------------------
__global__ __launch_bounds__(256) void k_bscatter(const int* __restrict__ src,
                                                  const int* __restrict__ dst,
                                                  int* __restrict__ gcursor,
                                                  int* __restrict__ packed,
                                                  int E4, int NB) {
    __shared__ int hist[NBMAX];
    __shared__ int cur[NBMAX];
    for (int i = threadIdx.x; i < NB; i += 256) hist[i] = 0;
    __syncthreads();
    int base = blockIdx.x * 2048;
    int4 dreg[8];
#pragma unroll
    for (int k = 0; k < 8; ++k) {
        int i4 = base + k * 256 + threadIdx.x;
        if (i4 < E4) {
            int4 d = ((const int4*)dst)[i4];
            dreg[k] = d;
            atomicAdd(&hist[d.x >> 7], 1);
            atomicAdd(&hist[d.y >> 7], 1);
            atomicAdd(&hist[d.z >> 7], 1);
            atomicAdd(&hist[d.w >> 7], 1);
        }
    }
    __syncthreads();
    for (int i = threadIdx.x; i < NB; i += 256) {
        int h = hist[i];
        cur[i] = h ? atomicAdd(&gcursor[i], h) : 0;
    }
    __syncthreads();
#pragma unroll
    for (int k = 0; k < 8; ++k) {
        int i4 = base + k * 256 + threadIdx.x;
        if (i4 < E4) {
            int4 s = ((const int4*)src)[i4];
            int4 d = dreg[k];
            int p;
            p = atomicAdd(&cur[d.x >> 7], 1); packed[p] = ((d.x & 127) << 20) | s.x;
            p = atomicAdd(&cur[d.y >> 7], 1); packed[p] = ((d.y & 127) << 20) | s.y;
            p = atomicAdd(&cur[d.z >> 7], 1); packed[p] = ((d.z & 127) << 20) | s.z;
            p = atomicAdd(&cur[d.w >> 7], 1); packed[p] = ((d.w & 127) << 20) | s.w;
        }
    }
}

// ---------------------------------------------------------------------------
// K4: bucket-local counting sort -> per-node CSR + nodestart.
// One block per bucket. Bucket slice staged in LDS (avg 2048, cap 12288);
// hist/scan/scatter all run from LDS. Global fallback for oversized buckets.
// ---------------------------------------------------------------------------
__global__ __launch_bounds__(256) void k_sort(const int* __restrict__ packed,
                                              const int* __restrict__ bstart,
                                              int* __restrict__ nodestart,
                                              int* __restrict__ csr, int N) {
    __shared__ int buf[SORT_CAP];
    __shared__ int hist[BW];
    __shared__ int curs[BW];
    __shared__ int wtot;
    int tid = threadIdx.x;
    int b = blockIdx.x;
    int st = bstart[b], en = bstart[b + 1], cnt = en - st;
    bool inlds = (cnt <= SORT_CAP);

    if (tid < BW) hist[tid] = 0;
    __syncthreads();
    if (inlds) {
        for (int i = tid; i < cnt; i += 256) {
            int e = packed[st + i];
            buf[i] = e;
            atomicAdd(&hist[e >> 20], 1);
        }
    } else {
        for (int i = tid; i < cnt; i += 256)
            atomicAdd(&hist[packed[st + i] >> 20], 1);
    }
    __syncthreads();

    int v = 0, excl = 0;
    if (tid < BW) {                       // threads 0..127 = waves 0,1
        int lane = tid & 63;
        v = hist[tid];
        int s = v;
#pragma unroll
        for (int off = 1; off < 64; off <<= 1) {
            int u = __shfl_up(s, off, 64);
            if (lane >= off) s += u;
        }
        excl = s - v;
        if (tid == 63) wtot = s;          // total of locals 0..63
    }
    __syncthreads();
    if (tid < BW) {
        if (tid >= 64) excl += wtot;
        curs[tid] = excl;
        int node = (b << 7) + tid;
        if (node < N) nodestart[node] = st + excl;
    }
    __syncthreads();
    if (inlds) {
        for (int i = tid; i < cnt; i += 256) {
            int e = buf[i];
            int p = atomicAdd(&curs[e >> 20], 1);
            csr[st + p] = e & 0xFFFFF;
        }
    } else {
        for (int i = tid; i < cnt; i += 256) {
            int e = packed[st + i];
            int p = atomicAdd(&curs[e >> 20], 1);
            csr[st + p] = e & 0xFFFFF;
        }
    }
}

// ---------------------------------------------------------------------------
// K5: y1 = x @ w1_l, z1 = x @ w1_r   (x: [N,128] f32 -> y1,z1: [N,16] f32)
// 64 rows/block; 4 lanes/row; each lane owns 8 outputs (f4 of y1 + f4 of z1).
// ---------------------------------------------------------------------------
__global__ __launch_bounds__(256) void k_xform(const float* __restrict__ x,
                                               const float* __restrict__ w1l,
                                               const float* __restrict__ w1r,
                                               float* __restrict__ y1,
                                               float* __restrict__ z1, int N) {
    __shared__ float wl[DD * HH];     // 8 KB, layout [d*16 + j]
    __shared__ float wr[DD * HH];     // 8 KB
    __shared__ float xt[64 * 132];    // 33.8 KB, row stride 132 f (33 f4)

    const int tid  = threadIdx.x;
    const int row0 = blockIdx.x * 64;

    {
        const float4* a = (const float4*)w1l;
        const float4* b = (const float4*)w1r;
        ((float4*)wl)[tid]       = a[tid];
        ((float4*)wl)[tid + 256] = a[tid + 256];
        ((float4*)wr)[tid]       = b[tid];
        ((float4*)wr)[tid + 256] = b[tid + 256];
    }
#pragma unroll
    for (int k = 0; k < 8; ++k) {     // 64 rows x 32 f4 = 2048 f4, 8/thread
        int idx = tid + k * 256;
        int r = idx >> 5, c = idx & 31;
        if (row0 + r < N)
            ((float4*)xt)[r * 33 + c] = ((const float4*)(x + (size_t)(row0 + r) * DD))[c];
    }
    __syncthreads();

    const int r = tid >> 2, seg = tid & 3;
    const int row = row0 + r;
    if (row >= N) return;
    float4 accy = {0.f, 0.f, 0.f, 0.f};
    float4 accz = {0.f, 0.f, 0.f, 0.f};
    const float* xrow = &xt[r * 132];
#pragma unroll 8
    for (int d = 0; d < DD; ++d) {
        float xv = xrow[d];
        float4 wl4 = *(const float4*)&wl[d * HH + seg * 4];
        float4 wr4 = *(const float4*)&wr[d * HH + seg * 4];
        accy.x += xv * wl4.x; accy.y += xv * wl4.y;
        accy.z += xv * wl4.z; accy.w += xv * wl4.w;
        accz.x += xv * wr4.x; accz.y += xv * wr4.y;
        accz.z += xv * wr4.z; accz.w += xv * wr4.w;
    }
    ((float4*)y1)[(size_t)row * 4 + seg] = accy;
    ((float4*)z1)[(size_t)row * 4 + seg] = accz;
}

// ---------------------------------------------------------------------------
// K6: layer-1 node-pull mean + fused bias/skip/relu.
// 4 lanes per node; lane seg owns a float4 column; 4-edge unroll.
//   h = relu(mean(y1[nbrs]) + b1 + z1)
// ---------------------------------------------------------------------------
__global__ __launch_bounds__(256) void k_agg(const int* __restrict__ csr,
                                             const int* __restrict__ nodestart,
                                             const float* __restrict__ feat,
                                             const float* __restrict__ z1,
                                             const float* __restrict__ b1,
                                             float* __restrict__ outv, int N) {
    int t = blockIdx.x * 256 + threadIdx.x;
    int node = t >> 2, seg = t & 3;
    if (node >= N) return;
    int st = nodestart[node], en = nodestart[node + 1];
    const float4* f4 = (const float4*)feat;

    float ax = 0.f, ay = 0.f, az = 0.f, aw = 0.f;
    int k = st;
    for (; k + 4 <= en; k += 4) {
        int s0 = csr[k], s1 = csr[k + 1], s2 = csr[k + 2], s3 = csr[k + 3];
        float4 a = f4[(size_t)(s0 * 4 + seg)];
        float4 b = f4[(size_t)(s1 * 4 + seg)];
        float4 c = f4[(size_t)(s2 * 4 + seg)];
        float4 d = f4[(size_t)(s3 * 4 + seg)];
        ax += (a.x + b.x) + (c.x + d.x);
        ay += (a.y + b.y) + (c.y + d.y);
        az += (a.z + b.z) + (c.z + d.z);
        aw += (a.w + b.w) + (c.w + d.w);
    }
    for (; k < en; ++k) {
        float4 a = f4[(size_t)(csr[k] * 4 + seg)];
        ax += a.x; ay += a.y; az += a.z; aw += a.w;
    }
    float inv = 1.f / fmaxf((float)(en - st), 1.f);
    size_t o = (size_t)node * 4 + seg;
    float4 z = ((const float4*)z1)[o];
    float4 bb = ((const float4*)b1)[seg];
    float4 r;
    r.x = fmaxf(ax * inv + bb.x + z.x, 0.f);
    r.y = fmaxf(ay * inv + bb.y + z.y, 0.f);
    r.z = fmaxf(az * inv + bb.z + z.z, 0.f);
    r.w = fmaxf(aw * inv + bb.w + z.w, 0.f);
    ((float4*)outv)[o] = r;
}

// ---------------------------------------------------------------------------
// K7: fused layer-2 on-demand aggregation + pair logits + BCE + final mean.
// 8 lanes per pair: slot s=sub>>2 (article1/2), seg=sub&3 (float4 column).
// Each slot walks its node's CSR slice gathering h (layer-2 agg on demand),
// dots with collapsed wsu vectors, 8-lane shfl reduce. Last block (ticket)
// writes out[0] = mean loss.
// ---------------------------------------------------------------------------
__global__ __launch_bounds__(256) void k_pair(const float* __restrict__ h,
                                              const int* __restrict__ csr,
                                              const int* __restrict__ nodestart,
                                              const int* __restrict__ a1,
                                              const int* __restrict__ a2,
                                              const int* __restrict__ labels,
                                              const float* __restrict__ wsu,
                                              float* __restrict__ out_logits,
                                              float* __restrict__ lacc,
                                              int* __restrict__ ticket,
                                              float* __restrict__ out0,
                                              int B, float invB) {
    __shared__ float lred[32];
    int t = blockIdx.x * 256 + threadIdx.x;
    int p = t >> 3, sub = t & 7;
    int s = sub >> 2, seg = sub & 3;
    int g = threadIdx.x >> 3;
    const float4* h4 = (const float4*)h;
    const float4* wsu4 = (const float4*)wsu;

    float myloss = 0.f;
    if (p < B) {
        int node = s ? a2[p] : a1[p];
        int st = nodestart[node], en = nodestart[node + 1];
        float ax = 0.f, ay = 0.f, az = 0.f, aw = 0.f;
        int k = st;
        for (; k + 2 <= en; k += 2) {
            int s0 = csr[k], s1 = csr[k + 1];
            float4 a = h4[(size_t)(s0 * 4 + seg)];
            float4 b = h4[(size_t)(s1 * 4 + seg)];
            ax += a.x + b.x; ay += a.y + b.y;
            az += a.z + b.z; aw += a.w + b.w;
        }
        if (k < en) {
            float4 a = h4[(size_t)(csr[k] * 4 + seg)];
            ax += a.x; ay += a.y; az += a.z; aw += a.w;
        }
        float inv = 1.f / fmaxf((float)(en - st), 1.f);
        float4 ul = wsu4[s * 4 + seg];          // agg-path vector
        float4 ur = wsu4[8 + s * 4 + seg];      // h-path vector
        float4 hn = h4[(size_t)node * 4 + seg];
        float v = (ax * ul.x + ay * ul.y + az * ul.z + aw * ul.w) * inv
                + (hn.x * ur.x + hn.y * ur.y + hn.z * ur.z + hn.w * ur.w);
#pragma unroll
        for (int off = 4; off; off >>= 1) v += __shfl_xor(v, off, 8);
        if (sub == 0) {
            float l = v + wsu[64] + wsu[65];
            out_logits[p] = l;
            float y = (float)labels[p];
            myloss = fmaxf(l, 0.f) - l * y + log1pf(expf(-fabsf(l)));
        }
    }
    if (sub == 0) lred[g] = myloss;
    __syncthreads();
    if (threadIdx.x == 0) {
        float ssum = 0.f;
#pragma unroll
        for (int k = 0; k < 32; ++k) ssum += lred[k];
        atomicAdd(lacc, ssum);
        __threadfence();
        int tk = atomicAdd(ticket, 1);
        if (tk == (int)gridDim.x - 1) {
            __threadfence();
            float total = atomicAdd(lacc, 0.f);   // atomic read-back
            out0[0] = total * invB;
        }
    }
}

// ---------------------------------------------------------------------------
extern "C" void kernel_launch(void* const* d_in, const int* in_sizes, int n_in,
                              void* d_out, int out_size, void* d_ws, size_t ws_size,
                              hipStream_t stream) {
    const float* x    = (const float*)d_in[0];
    const float* w1l  = (const float*)d_in[1];
    const float* b1   = (const float*)d_in[2];
    const float* w1r  = (const float*)d_in[3];
    const float* w2l  = (const float*)d_in[4];
    const float* b2v  = (const float*)d_in[5];
    const float* w2r  = (const float*)d_in[6];
    const float* wc   = (const float*)d_in[7];
    const float* bc   = (const float*)d_in[8];
    const int*   ei   = (const int*)d_in[9];
    const int*   a1   = (const int*)d_in[10];
    const int*   a2   = (const int*)d_in[11];
    const int*   lab  = (const int*)d_in[12];

    const int N = in_sizes[0] / DD;
    const int E = in_sizes[9] / 2;
    const int B = in_sizes[10];
    const int NB = (N + BW - 1) / BW;       // 782 for N=100000 (needs N < 2^20)

    const int* src = ei;
    const int* dst = ei + E;

    // workspace layout
    char* ws = (char*)d_ws;
    const size_t NH4 = (size_t)N * HH * 4;
    float* wsu     = (float*)ws;                             // 512 B
    float* y1      = (float*)(ws + 512);                     // [N,16]
    float* z1      = (float*)(ws + 512 + NH4);
    float* h       = (float*)(ws + 512 + 2 * NH4);
    int*   packed  = (int*)  (ws + 512 + 3 * NH4);           // [E]
    int*   csr     = (int*)  (ws + 512 + 3 * NH4 + (size_t)E * 4);  // [E]
    char*  p4      = ws + 512 + 3 * NH4 + 2 * (size_t)E * 4;
    int*   nodest  = (int*)p4;                               // [N+1]
    int*   bstart  = (int*)(p4 + ((size_t)N + 1) * 4);       // [NB+1]
    int*   gcursor = (int*)(p4 + ((size_t)N + 1) * 4 + ((size_t)NB + 1) * 4);  // [NB]
    int*   bcnt    = (int*)(p4 + ((size_t)N + 1) * 4 + (2 * (size_t)NB + 1) * 4); // [NB] zeroed
    float* lacc    = (float*)(p4 + ((size_t)N + 1) * 4 + (3 * (size_t)NB + 1) * 4);// [1] zeroed
    int*   ticket  = (int*)  (p4 + ((size_t)N + 1) * 4 + (3 * (size_t)NB + 1) * 4 + 4); // [1] zeroed

    float* out = (float*)d_out;       // out[0] = loss, out[1..B] = logits

    // zero bcnt + lacc + ticket (contiguous)
    hipMemsetAsync((void*)bcnt, 0, (size_t)NB * 4 + 8, stream);

    const int E4 = E / 4;
    const int chunks = (E4 + 2047) / 2048;   // 8192 edges per chunk

    // fused: bucket histogram + classifier-collapse prep
    k_bcount<<<chunks + 1, 256, 0, stream>>>(dst, bcnt, E4, NB, chunks,
                                             w2l, w2r, b2v, wc, bc, wsu);
    k_bscan<<<1, 1024, 0, stream>>>(bcnt, bstart, gcursor, nodest, NB, N, E);
    k_bscatter<<<chunks, 256, 0, stream>>>(src, dst, gcursor, packed, E4, NB);
    k_sort<<<NB, 256, 0, stream>>>(packed, bstart, nodest, csr, N);

    k_xform<<<(N + 63) / 64, 256, 0, stream>>>(x, w1l, w1r, y1, z1, N);

    // layer 1: h = relu(mean(y1[nbrs]) + b1 + z1)
    k_agg<<<((N * 4) + 255) / 256, 256, 0, stream>>>(csr, nodest, y1, z1, b1, h, N);

    // fused: on-demand layer-2 agg + logits + BCE + final mean
    k_pair<<<(B * 8 + 255) / 256, 256, 0, stream>>>(h, csr, nodest, a1, a2, lab, wsu,
                                                    out + 1, lacc, ticket, out,
                                                    B, 1.0f / (float)B);
}